// Round 4
// baseline (586.041 us; speedup 1.0000x reference)
//
#include <hip/hip_runtime.h>
#include <hip/hip_bf16.h>

#define IN_DIM   128
#define HIDDEN   256
#define OUT_DIM  128
#define N_NODES  100000
#define N_EDGES  500000
#define N_ROWS   (2 * N_EDGES)   // 1,000,000 rows (2 MC x edges)

typedef __bf16 bf16x8  __attribute__((ext_vector_type(8)));
typedef float  f32x16  __attribute__((ext_vector_type(16)));

// ws: 12 chunks x 16384 B. Chunk = 32 output-cols (n) x 512 B (K=256 bf16,
// XOR-swizzled by ((n&7)<<4) in 16B granules). Chunks 0..7 = W1^T, 8..11 = W2^T.
#define W1S_OFF 0
#define W2S_OFF 131072

__global__ void prep_weights(const float* __restrict__ W1,
                             const float* __restrict__ W2,
                             unsigned char* __restrict__ ws) {
  int t = blockIdx.x * 256 + threadIdx.x;
  if (t < HIDDEN * HIDDEN) {           // W1: [k=256][n=256] row-major input
    int n = t & 255, k = t >> 8;
    __bf16 b = (__bf16)W1[k * HIDDEN + n];
    int byte = W1S_OFF + n * 512 + ((k * 2) ^ ((n & 7) << 4));
    *reinterpret_cast<__bf16*>(ws + byte) = b;
  } else {
    int t2 = t - HIDDEN * HIDDEN;
    if (t2 < HIDDEN * OUT_DIM) {       // W2: [k=256][n=128]
      int n = t2 & 127, k = t2 >> 7;
      __bf16 b = (__bf16)W2[k * OUT_DIM + n];
      int byte = W2S_OFF + n * 512 + ((k * 2) ^ ((n & 7) << 4));
      *reinterpret_cast<__bf16*>(ws + byte) = b;
    }
  }
}

static __device__ __forceinline__ unsigned pack_bf16(float a, float b) {
  __bf16 x = (__bf16)a, y = (__bf16)b;
  unsigned short ux = __builtin_bit_cast(unsigned short, x);
  unsigned short uy = __builtin_bit_cast(unsigned short, y);
  return (unsigned)ux | ((unsigned)uy << 16);
}

// 4 waves/block share one double-buffered weight chunk stream (32 KB LDS).
// Each wave: 32 edges, swapped L1 (mfma(W,x)), in-register transpose via
// v_permlane32_swap, standard L2. Tail: 32-row tiles are wave-uniform valid.
__global__ __launch_bounds__(256, 4)
void edge_mlp(const int* __restrict__ eidx,
              const float* __restrict__ x,
              const float* __restrict__ b1,
              const float* __restrict__ b2,
              const unsigned char* __restrict__ ws,
              float* __restrict__ out) {
  __shared__ __align__(16) unsigned char wbuf[2][16384];

  const int tid  = threadIdx.x;
  const int wv   = tid >> 6;           // wave 0..3
  const int lane = tid & 63;
  const int el   = lane & 31;          // edge within wave tile
  const int hi   = lane >> 5;          // k half

  const long base = (long)blockIdx.x * 128;
  const long gr   = base + wv * 32 + el;
  const long grc  = (gr < N_ROWS) ? gr : (N_ROWS - 1);   // clamped gather row
  const bool wvalid = (base + wv * 32) < N_ROWS;          // wave-uniform
  const int  mc   = (grc >= N_EDGES) ? 1 : 0;
  const int  e    = (int)(grc - (long)mc * N_EDGES);
  const int  sn   = eidx[e];
  const int  dn   = eidx[N_EDGES + e];
  const float* xs = x + ((long)mc * N_NODES + sn) * IN_DIM;
  const float* xd = x + ((long)mc * N_NODES + dn) * IN_DIM;

  // ---- x fragments (B of swapped L1, 32x32x16): lane holds edge=el,
  //      k = s*16 + hi*8 + j (8 consecutive) ----
  bf16x8 a1[16];
#pragma unroll
  for (int s = 0; s < 16; ++s) {
    int k0 = s * 16 + hi * 8;
    const float* p = (s < 8) ? (xs + k0) : (xd + (k0 - IN_DIM));
    float4 f0 = *reinterpret_cast<const float4*>(p);
    float4 f1 = *reinterpret_cast<const float4*>(p + 4);
    bf16x8 a;
    a[0] = (__bf16)f0.x; a[1] = (__bf16)f0.y; a[2] = (__bf16)f0.z; a[3] = (__bf16)f0.w;
    a[4] = (__bf16)f1.x; a[5] = (__bf16)f1.y; a[6] = (__bf16)f1.z; a[7] = (__bf16)f1.w;
    a1[s] = a;
  }

  // 256 threads copy one 16384 B chunk in 4 sweeps of 4096 B
#define STAGE(t, b)                                                            \
  do {                                                                         \
    const unsigned char* g_ = ws + (t) * 16384;                                \
    _Pragma("unroll")                                                          \
    for (int i_ = 0; i_ < 4; ++i_) {                                           \
      __builtin_amdgcn_global_load_lds(                                        \
          (const __attribute__((address_space(1))) unsigned int*)(g_ + i_ * 4096 + tid * 16), \
          (__attribute__((address_space(3))) unsigned int*)(&wbuf[b][i_ * 4096 + tid * 16]),  \
          16, 0, 0);                                                           \
    }                                                                          \
  } while (0)

  STAGE(0, 0);
  __syncthreads();

  const int rowb = el * 512;
  const int swz  = (el & 7) << 4;

  bf16x8 a2[16];

  // ---- layer 1 (swapped): per 32-hcol chunk cc, D[hcol][edge] = W1^T x ----
#pragma unroll
  for (int cc = 0; cc < 8; ++cc) {
    STAGE(cc + 1, (cc + 1) & 1);        // chunks 1..8
    f32x16 acc = {};
#pragma unroll
    for (int ks = 0; ks < 16; ++ks) {
      bf16x8 wf = *reinterpret_cast<const bf16x8*>(
          &wbuf[cc & 1][rowb + ((ks * 32 + hi * 16) ^ swz)]);
      acc = __builtin_amdgcn_mfma_f32_32x32x16_bf16(wf, a1[ks], acc, 0, 0, 0);
    }
    // C: col=edge=el, row m=(reg&3)+8*(reg>>2)+4*hi; hcol = cc*32 + m
    float4 bv0 = *reinterpret_cast<const float4*>(b1 + cc * 32 + hi * 4);
    float4 bv1 = *reinterpret_cast<const float4*>(b1 + cc * 32 + 8 + hi * 4);
    float4 bv2 = *reinterpret_cast<const float4*>(b1 + cc * 32 + 16 + hi * 4);
    float4 bv3 = *reinterpret_cast<const float4*>(b1 + cc * 32 + 24 + hi * 4);
    unsigned w0 = pack_bf16(fmaxf(acc[0] + bv0.x, 0.f),  fmaxf(acc[1] + bv0.y, 0.f));
    unsigned w1 = pack_bf16(fmaxf(acc[2] + bv0.z, 0.f),  fmaxf(acc[3] + bv0.w, 0.f));
    unsigned w2 = pack_bf16(fmaxf(acc[4] + bv1.x, 0.f),  fmaxf(acc[5] + bv1.y, 0.f));
    unsigned w3 = pack_bf16(fmaxf(acc[6] + bv1.z, 0.f),  fmaxf(acc[7] + bv1.w, 0.f));
    unsigned w4 = pack_bf16(fmaxf(acc[8] + bv2.x, 0.f),  fmaxf(acc[9] + bv2.y, 0.f));
    unsigned w5 = pack_bf16(fmaxf(acc[10] + bv2.z, 0.f), fmaxf(acc[11] + bv2.w, 0.f));
    unsigned w6 = pack_bf16(fmaxf(acc[12] + bv3.x, 0.f), fmaxf(acc[13] + bv3.y, 0.f));
    unsigned w7 = pack_bf16(fmaxf(acc[14] + bv3.z, 0.f), fmaxf(acc[15] + bv3.w, 0.f));
    // half-wave exchange: vdst' = (a.row0, b.row0); vsrc' = (a.row1, b.row1)
    asm("v_permlane32_swap_b32 %0, %1" : "+v"(w0), "+v"(w2));
    asm("v_permlane32_swap_b32 %0, %1" : "+v"(w1), "+v"(w3));
    asm("v_permlane32_swap_b32 %0, %1" : "+v"(w4), "+v"(w6));
    asm("v_permlane32_swap_b32 %0, %1" : "+v"(w5), "+v"(w7));
    uint4 fe; fe.x = w0; fe.y = w1; fe.z = w2; fe.w = w3;
    uint4 fo; fo.x = w4; fo.y = w5; fo.z = w6; fo.w = w7;
    a2[2 * cc]     = __builtin_bit_cast(bf16x8, fe);
    a2[2 * cc + 1] = __builtin_bit_cast(bf16x8, fo);
    __syncthreads();
  }

  // ---- layer 2 (standard): out[edge][ocol] = h @ W2 + b2 ----
#pragma unroll
  for (int oc = 0; oc < 4; ++oc) {
    const int t = 8 + oc;
    if (t + 1 < 12) STAGE(t + 1, (t + 1) & 1);
    f32x16 acc = {};
#pragma unroll
    for (int kk = 0; kk < 16; ++kk) {
      bf16x8 wf = *reinterpret_cast<const bf16x8*>(
          &wbuf[t & 1][rowb + ((kk * 32 + hi * 16) ^ swz)]);
      acc = __builtin_amdgcn_mfma_f32_32x32x16_bf16(a2[kk], wf, acc, 0, 0, 0);
    }
    if (wvalid) {
      float bvo = b2[oc * 32 + el];
      const long r0 = base + wv * 32;
#pragma unroll
      for (int reg = 0; reg < 16; ++reg) {
        int m = (reg & 3) + 8 * (reg >> 2) + 4 * hi;
        out[(r0 + m) * OUT_DIM + oc * 32 + el] = acc[reg] + bvo;
      }
    }
    if (oc < 3) __syncthreads();
  }
#undef STAGE
}

extern "C" void kernel_launch(void* const* d_in, const int* in_sizes, int n_in,
                              void* d_out, int out_size, void* d_ws, size_t ws_size,
                              hipStream_t stream) {
  const int*   eidx = (const int*)d_in[0];
  const float* x    = (const float*)d_in[1];
  const float* b1   = (const float*)d_in[3];
  const float* b2   = (const float*)d_in[5];
  float* out = (float*)d_out;
  unsigned char* ws = (unsigned char*)d_ws;

  prep_weights<<<(HIDDEN * HIDDEN + HIDDEN * OUT_DIM) / 256, 256, 0, stream>>>(
      (const float*)d_in[2], (const float*)d_in[4], ws);

  // 128 rows per block, tail block guarded (wave-uniform 32-row tiles)
  edge_mlp<<<(N_ROWS + 127) / 128, 256, 0, stream>>>(eidx, x, b1, b2, ws, out);
  (void)in_sizes; (void)n_in; (void)out_size; (void)ws_size;
}

// Round 6
// 362.520 us; speedup vs baseline: 1.6166x; 1.6166x over previous
//
#include <hip/hip_runtime.h>
#include <hip/hip_bf16.h>

#define IN_DIM   128
#define HIDDEN   256
#define OUT_DIM  128
#define N_NODES  100000
#define N_EDGES  500000
#define N_ROWS   (2 * N_EDGES)   // 1,000,000 rows (2 MC x edges)

typedef __bf16 bf16x8  __attribute__((ext_vector_type(8)));
typedef float  f32x16  __attribute__((ext_vector_type(16)));

// ws: 12 chunks x 16384 B. Chunk = 32 output-cols (n) x 512 B (K=256 bf16,
// XOR-swizzled by ((n&7)<<4) in 16B granules). Chunks 0..7 = W1^T, 8..11 = W2^T.
#define W1S_OFF 0
#define W2S_OFF 131072

__global__ void prep_weights(const float* __restrict__ W1,
                             const float* __restrict__ W2,
                             unsigned char* __restrict__ ws) {
  int t = blockIdx.x * 256 + threadIdx.x;
  if (t < HIDDEN * HIDDEN) {           // W1: [k=256][n=256] row-major input
    int n = t & 255, k = t >> 8;
    __bf16 b = (__bf16)W1[k * HIDDEN + n];
    int byte = W1S_OFF + n * 512 + ((k * 2) ^ ((n & 7) << 4));
    *reinterpret_cast<__bf16*>(ws + byte) = b;
  } else {
    int t2 = t - HIDDEN * HIDDEN;
    if (t2 < HIDDEN * OUT_DIM) {       // W2: [k=256][n=128]
      int n = t2 & 127, k = t2 >> 7;
      __bf16 b = (__bf16)W2[k * OUT_DIM + n];
      int byte = W2S_OFF + n * 512 + ((k * 2) ^ ((n & 7) << 4));
      *reinterpret_cast<__bf16*>(ws + byte) = b;
    }
  }
}

static __device__ __forceinline__ unsigned pack_bf16(float a, float b) {
  __bf16 x = (__bf16)a, y = (__bf16)b;
  unsigned short ux = __builtin_bit_cast(unsigned short, x);
  unsigned short uy = __builtin_bit_cast(unsigned short, y);
  return (unsigned)ux | ((unsigned)uy << 16);
}

// Round-3 compute structure (proven): 128 threads = 2 waves x 32 edges,
// swapped L1 mfma(W,x) + v_permlane32_swap register transpose, standard L2.
// Staging: round-1 structure (proven): SINGLE 16 KB buffer, 2 barriers per
// chunk (barrier -> STAGE -> barrier -> compute). LDS 16 KB -> ~10 blocks/CU
// (round 3's 32 KB double-buffer capped occupancy at 22%).
// NOTE: do NOT use 256-thread/4-wave variants of this kernel — the >128-VGPR
// 256-thread build miscompiles (round 5: deterministic absmax 1.75).
__global__ __launch_bounds__(128)
void edge_mlp(const int* __restrict__ eidx,
              const float* __restrict__ x,
              const float* __restrict__ b1,
              const float* __restrict__ b2,
              const unsigned char* __restrict__ ws,
              float* __restrict__ out) {
  __shared__ __align__(16) unsigned char wbuf[16384];

  const int tid  = threadIdx.x;
  const int wv   = tid >> 6;           // wave 0..1
  const int lane = tid & 63;
  const int el   = lane & 31;          // edge within wave tile
  const int hi   = lane >> 5;          // k half

  const long base = (long)blockIdx.x * 64;
  const long gr   = base + wv * 32 + el;
  const int  mc   = (gr >= N_EDGES) ? 1 : 0;
  const int  e    = (int)(gr - (long)mc * N_EDGES);
  const int  sn   = eidx[e];
  const int  dn   = eidx[N_EDGES + e];
  const float* xs = x + ((long)mc * N_NODES + sn) * IN_DIM;
  const float* xd = x + ((long)mc * N_NODES + dn) * IN_DIM;

  // ---- x fragments (B of swapped L1, 32x32x16): lane holds edge=el,
  //      k = s*16 + hi*8 + j (8 consecutive) ----
  bf16x8 a1[16];
#pragma unroll
  for (int s = 0; s < 16; ++s) {
    int k0 = s * 16 + hi * 8;
    const float* p = (s < 8) ? (xs + k0) : (xd + (k0 - IN_DIM));
    float4 f0 = *reinterpret_cast<const float4*>(p);
    float4 f1 = *reinterpret_cast<const float4*>(p + 4);
    bf16x8 a;
    a[0] = (__bf16)f0.x; a[1] = (__bf16)f0.y; a[2] = (__bf16)f0.z; a[3] = (__bf16)f0.w;
    a[4] = (__bf16)f1.x; a[5] = (__bf16)f1.y; a[6] = (__bf16)f1.z; a[7] = (__bf16)f1.w;
    a1[s] = a;
  }

  // 128 threads copy one 16384 B chunk in 8 sweeps of 2048 B
#define STAGE(t)                                                               \
  do {                                                                         \
    const unsigned char* g_ = ws + (t) * 16384;                                \
    _Pragma("unroll")                                                          \
    for (int i_ = 0; i_ < 8; ++i_) {                                           \
      __builtin_amdgcn_global_load_lds(                                        \
          (const __attribute__((address_space(1))) unsigned int*)(g_ + i_ * 2048 + tid * 16), \
          (__attribute__((address_space(3))) unsigned int*)(&wbuf[i_ * 2048 + tid * 16]),     \
          16, 0, 0);                                                           \
    }                                                                          \
  } while (0)

  const int rowb = el * 512;
  const int swz  = (el & 7) << 4;

  bf16x8 a2[16];

  // ---- layer 1 (swapped): per 32-hcol chunk cc, D[hcol][edge] = W1^T x ----
#pragma unroll
  for (int cc = 0; cc < 8; ++cc) {
    __syncthreads();                    // previous chunk's readers done
    STAGE(cc);
    __syncthreads();                    // stage drained (vmcnt0 + barrier)
    f32x16 acc = {};
#pragma unroll
    for (int ks = 0; ks < 16; ++ks) {
      bf16x8 wf = *reinterpret_cast<const bf16x8*>(
          &wbuf[rowb + ((ks * 32 + hi * 16) ^ swz)]);
      acc = __builtin_amdgcn_mfma_f32_32x32x16_bf16(wf, a1[ks], acc, 0, 0, 0);
    }
    // C: col=edge=el, row m=(reg&3)+8*(reg>>2)+4*hi; hcol = cc*32 + m
    float4 bv0 = *reinterpret_cast<const float4*>(b1 + cc * 32 + hi * 4);
    float4 bv1 = *reinterpret_cast<const float4*>(b1 + cc * 32 + 8 + hi * 4);
    float4 bv2 = *reinterpret_cast<const float4*>(b1 + cc * 32 + 16 + hi * 4);
    float4 bv3 = *reinterpret_cast<const float4*>(b1 + cc * 32 + 24 + hi * 4);
    unsigned w0 = pack_bf16(fmaxf(acc[0] + bv0.x, 0.f),  fmaxf(acc[1] + bv0.y, 0.f));
    unsigned w1 = pack_bf16(fmaxf(acc[2] + bv0.z, 0.f),  fmaxf(acc[3] + bv0.w, 0.f));
    unsigned w2 = pack_bf16(fmaxf(acc[4] + bv1.x, 0.f),  fmaxf(acc[5] + bv1.y, 0.f));
    unsigned w3 = pack_bf16(fmaxf(acc[6] + bv1.z, 0.f),  fmaxf(acc[7] + bv1.w, 0.f));
    unsigned w4 = pack_bf16(fmaxf(acc[8] + bv2.x, 0.f),  fmaxf(acc[9] + bv2.y, 0.f));
    unsigned w5 = pack_bf16(fmaxf(acc[10] + bv2.z, 0.f), fmaxf(acc[11] + bv2.w, 0.f));
    unsigned w6 = pack_bf16(fmaxf(acc[12] + bv3.x, 0.f), fmaxf(acc[13] + bv3.y, 0.f));
    unsigned w7 = pack_bf16(fmaxf(acc[14] + bv3.z, 0.f), fmaxf(acc[15] + bv3.w, 0.f));
    // half-wave exchange: vdst' = (a.row0, b.row0); vsrc' = (a.row1, b.row1)
    asm("v_permlane32_swap_b32 %0, %1" : "+v"(w0), "+v"(w2));
    asm("v_permlane32_swap_b32 %0, %1" : "+v"(w1), "+v"(w3));
    asm("v_permlane32_swap_b32 %0, %1" : "+v"(w4), "+v"(w6));
    asm("v_permlane32_swap_b32 %0, %1" : "+v"(w5), "+v"(w7));
    uint4 fe; fe.x = w0; fe.y = w1; fe.z = w2; fe.w = w3;
    uint4 fo; fo.x = w4; fo.y = w5; fo.z = w6; fo.w = w7;
    a2[2 * cc]     = __builtin_bit_cast(bf16x8, fe);
    a2[2 * cc + 1] = __builtin_bit_cast(bf16x8, fo);
  }

  // ---- layer 2 (standard): out[edge][ocol] = h @ W2 + b2 ----
#pragma unroll
  for (int oc = 0; oc < 4; ++oc) {
    __syncthreads();
    STAGE(8 + oc);
    __syncthreads();
    f32x16 acc = {};
#pragma unroll
    for (int kk = 0; kk < 16; ++kk) {
      bf16x8 wf = *reinterpret_cast<const bf16x8*>(
          &wbuf[rowb + ((kk * 32 + hi * 16) ^ swz)]);
      acc = __builtin_amdgcn_mfma_f32_32x32x16_bf16(a2[kk], wf, acc, 0, 0, 0);
    }
    float bvo = b2[oc * 32 + el];
    const long r0 = base + wv * 32;
#pragma unroll
    for (int reg = 0; reg < 16; ++reg) {
      int m = (reg & 3) + 8 * (reg >> 2) + 4 * hi;
      out[(r0 + m) * OUT_DIM + oc * 32 + el] = acc[reg] + bvo;
    }
  }
#undef STAGE
}

extern "C" void kernel_launch(void* const* d_in, const int* in_sizes, int n_in,
                              void* d_out, int out_size, void* d_ws, size_t ws_size,
                              hipStream_t stream) {
  const int*   eidx = (const int*)d_in[0];
  const float* x    = (const float*)d_in[1];
  const float* b1   = (const float*)d_in[3];
  const float* b2   = (const float*)d_in[5];
  float* out = (float*)d_out;
  unsigned char* ws = (unsigned char*)d_ws;

  prep_weights<<<(HIDDEN * HIDDEN + HIDDEN * OUT_DIM) / 256, 256, 0, stream>>>(
      (const float*)d_in[2], (const float*)d_in[4], ws);

  // 64 rows per block, exact grid (no tail)
  edge_mlp<<<N_ROWS / 64, 128, 0, stream>>>(eidx, x, b1, b2, ws, out);
  (void)in_sizes; (void)n_in; (void)out_size; (void)ws_size;
}